// Round 1
// baseline (745.371 us; speedup 1.0000x reference)
//
#include <hip/hip_runtime.h>
#include <cstddef>
#include <cstdint>

#define Tn 512
#define Bn 32
#define Hn 512
static const size_t PLANE = 8388608; // Bn*Tn*Hn

typedef float f32x4 __attribute__((ext_vector_type(4)));
typedef __bf16 bf16x8 __attribute__((ext_vector_type(8)));
typedef _Float16 h2 __attribute__((ext_vector_type(2)));

__device__ __forceinline__ float sigm(float x) { return 1.0f / (1.0f + __expf(-x)); }
__device__ __forceinline__ float tanh_fast(float x) { return 2.0f / (1.0f + __expf(-2.0f * x)) - 1.0f; }
__device__ __forceinline__ unsigned short f2bf(float f) {
    unsigned int u = __float_as_uint(f);
    u += 0x7FFF + ((u >> 16) & 1);   // RNE
    return (unsigned short)(u >> 16);
}

// ---------------- conversion kernels ----------------

__global__ __launch_bounds__(256) void conv_x(const float* __restrict__ x,
                                              unsigned short* __restrict__ xbf) {
    const int i = blockIdx.x * 256 + threadIdx.x;  // 32*514*64
    const int c8 = i & 63;
    const int tp = (i >> 6) % 514;
    const int b  = (i >> 6) / 514;
    unsigned short v[8];
    if (tp == 0 || tp == 513) {
#pragma unroll
        for (int j = 0; j < 8; ++j) v[j] = 0;
    } else {
        const float* s = x + ((size_t)(tp - 1) * Bn + b) * 512 + c8 * 8;
#pragma unroll
        for (int j = 0; j < 8; ++j) v[j] = f2bf(s[j]);
    }
    unsigned short* d = xbf + ((size_t)b * 514 + tp) * 512 + c8 * 8;
    *(uint4*)d = *(const uint4*)v;
}

// both weight tensors: [dir][g][o][c][tap] fp32 -> [dir][m'=o*4+g][k'=tap*Cin+c] bf16
__global__ __launch_bounds__(256) void conv_w2(const float* __restrict__ w0,
                                               const float* __restrict__ w1,
                                               unsigned short* __restrict__ w0bf,
                                               unsigned short* __restrict__ w1bf) {
    int i = blockIdx.x * 256 + threadIdx.x;   // 4194304 + 8388608
    const float* src;
    unsigned short* dst;
    int Cin;
    if (i < 4194304) { src = w0; dst = w0bf; Cin = 512; }
    else { i -= 4194304; src = w1; dst = w1bf; Cin = 1024; }
    const int K = 2 * Cin;
    const int dm2 = i / K;            // dir*2048 + m'
    const int kp = i - dm2 * K;
    const int dir = dm2 >> 11;
    const int mp = dm2 & 2047;
    const int o = mp >> 2;
    const int g = mp & 3;
    const int tap = (kp >= Cin) ? 1 : 0;
    const int c = kp - tap * Cin;
    dst[i] = f2bf(src[((((size_t)dir * 4 + g) * 512 + o) * Cin + c) * 2 + tap]);
}

__global__ __launch_bounds__(256) void zero_h1pad(unsigned short* __restrict__ h1bf) {
    const int i = blockIdx.x * 256 + threadIdx.x;  // 65536
    const int c = i & 1023;
    const int b = (i >> 10) & 31;
    const int tp = (i >> 15) ? 513 : 0;
    h1bf[((size_t)b * 514 + tp) * 1024 + c] = 0;
}

// ---------------- 256x256-tile 8-wave 4-phase MFMA gate GEMM ----------------
// grid (64 n-tiles, 16): blockIdx.y = dir*8 + mtile (256 m-rows each).
// C[m'=o*4+g][n=(b,t)]; fragment f32x4 = {z,f,o,i} of one (o,n).
// K-loop: double-buffered LDS (2 x (A 32K + B 32K) = 128 KiB), prefetch step s+1
// issued at top of step s (phase 0), awaited at end of phase 3 (T3/T4);
// per-phase barrier pairs + setprio around MFMA clusters (T5);
// XOR-swizzled LDS via pre-swizzled global source (T2, m173 pattern).
template <int CIN>
__global__ __launch_bounds__(512, 2) void gate_gemm_bf16(
    const unsigned short* __restrict__ Wbf,  // [2][2048][2*CIN], rows m'=o*4+g
    const unsigned short* __restrict__ Xbf,  // [32][514][CIN]
    const float* __restrict__ bias,          // [2][4][512]
    h2* __restrict__ fiz,                    // [2][16384][512]
    _Float16* __restrict__ osb,              // [2][16384][512]
    float* __restrict__ Fsum,                // [2][8][32][512]
    float* __restrict__ Ssum)                // [2][8][32][512]
{
    __shared__ __align__(16) unsigned char smem[131072];
    unsigned short* lds0 = (unsigned short*)smem;  // [2 buf][A 16384][B 16384] elems

    const int tid = threadIdx.x;
    const int lane = tid & 63;
    const int wave = tid >> 6;
    const int wm = wave >> 2;          // 0..1 (M half)
    const int wn = wave & 3;           // 0..3 (N quarter)
    const int n0 = blockIdx.x * 256;
    const int dir = blockIdx.y >> 3;
    const int m0 = (blockIdx.y & 7) * 256;
    const int S0 = CIN / 64;
    const int NS = 2 * S0;             // K-steps (tap-major)
    const int dstep = dir ? -CIN : CIN;

    const unsigned short* Wb = Wbf + (size_t)dir * 2048 * 2 * CIN;

    // ---- hoisted stage sources (XOR swizzle baked into global address) ----
    const unsigned short* pAs[4];
    const unsigned short* pBs[4];
#pragma unroll
    for (int r = 0; r < 4; ++r) {
        const int q = r * 512 + tid;       // 0..2047 -> row 0..255, j 0..7
        const int row = q >> 3;
        const int j = q & 7;
        const int kk = j ^ ((row >> 1) & 7);
        pAs[r] = Wb + (size_t)(m0 + row) * (2 * CIN) + kk * 8;
        const int n = n0 + row;
        const int t = n & 511;
        const int b = n >> 9;
        const int tp0 = dir ? (513 - t) : t;
        pBs[r] = Xbf + ((size_t)b * 514 + tp0) * CIN + kk * 8;
    }

    // ---- hoisted LDS fragment offsets (elements); kh=1 is ^32 ----
    const int jr0 = lane >> 4;
    int offA[8], offB[4];
#pragma unroll
    for (int f = 0; f < 8; ++f) {
        const int ma = wm * 128 + f * 16 + (lane & 15);
        offA[f] = ma * 64 + (jr0 ^ ((ma >> 1) & 7)) * 8;
    }
#pragma unroll
    for (int f = 0; f < 4; ++f) {
        const int nb = wn * 64 + f * 16 + (lane & 15);
        offB[f] = nb * 64 + (jr0 ^ ((nb >> 1) & 7)) * 8;
    }

    f32x4 acc[8][4] = {};

#define GL(P, D) __builtin_amdgcn_global_load_lds( \
        (const __attribute__((address_space(1))) unsigned int*)(P), \
        (__attribute__((address_space(3))) unsigned int*)(D), 16, 0, 0)

#define STAGE(ks, sel) do { \
    const int tap_ = ((ks) >= S0) ? 1 : 0; \
    const int aoff_ = tap_ * CIN + ((ks) - tap_ * S0) * 64; \
    const int boff_ = tap_ * dstep + ((ks) - tap_ * S0) * 64; \
    unsigned short* Ad_ = lds0 + (sel) * 32768 + tid * 8; \
    unsigned short* Bd_ = Ad_ + 16384; \
    GL(pAs[0] + aoff_, Ad_);          GL(pBs[0] + boff_, Bd_); \
    GL(pAs[1] + aoff_, Ad_ + 4096);   GL(pBs[1] + boff_, Bd_ + 4096); \
    GL(pAs[2] + aoff_, Ad_ + 8192);   GL(pBs[2] + boff_, Bd_ + 8192); \
    GL(pAs[3] + aoff_, Ad_ + 12288);  GL(pBs[3] + boff_, Bd_ + 12288); \
} while (0)

#define RD_A(mh, kh) do { \
    af[0] = *(const bf16x8*)&Ab[offA[(mh)*4+0] ^ ((kh)*32)]; \
    af[1] = *(const bf16x8*)&Ab[offA[(mh)*4+1] ^ ((kh)*32)]; \
    af[2] = *(const bf16x8*)&Ab[offA[(mh)*4+2] ^ ((kh)*32)]; \
    af[3] = *(const bf16x8*)&Ab[offA[(mh)*4+3] ^ ((kh)*32)]; \
} while (0)

#define RD_B(kh) do { \
    bfr[0] = *(const bf16x8*)&Bb[offB[0] ^ ((kh)*32)]; \
    bfr[1] = *(const bf16x8*)&Bb[offB[1] ^ ((kh)*32)]; \
    bfr[2] = *(const bf16x8*)&Bb[offB[2] ^ ((kh)*32)]; \
    bfr[3] = *(const bf16x8*)&Bb[offB[3] ^ ((kh)*32)]; \
} while (0)

#define MM(mh) do { \
    _Pragma("unroll") \
    for (int f_ = 0; f_ < 4; ++f_) { \
        _Pragma("unroll") \
        for (int fn_ = 0; fn_ < 4; ++fn_) \
            acc[(mh)*4+f_][fn_] = __builtin_amdgcn_mfma_f32_16x16x32_bf16( \
                af[f_], bfr[fn_], acc[(mh)*4+f_][fn_], 0, 0, 0); \
    } \
} while (0)

#define LGKM0 do { asm volatile("s_waitcnt lgkmcnt(0)" ::: "memory"); \
                   __builtin_amdgcn_sched_barrier(0); } while (0)

    // prologue: stage step 0 into buf0, full drain once
    STAGE(0, 0);
    asm volatile("s_waitcnt vmcnt(0)" ::: "memory");
    __builtin_amdgcn_s_barrier();

#pragma unroll 2
    for (int s = 0; s < NS; ++s) {
        asm volatile("" ::: "memory");   // pin GLs below the preceding barrier
        const unsigned short* Ab = lds0 + (s & 1) * 32768;
        const unsigned short* Bb = Ab + 16384;
        bf16x8 af[4], bfr[4];
        const bool pre = (s + 1 < NS);
        // ---- P0: issue next-step stage, read (mh0,kh0)+B(kh0), MFMA quad ----
        if (pre) STAGE(s + 1, (s & 1) ^ 1);
        RD_B(0); RD_A(0, 0);
        __builtin_amdgcn_s_barrier();
        LGKM0;
        __builtin_amdgcn_s_setprio(1); MM(0); __builtin_amdgcn_s_setprio(0);
        __builtin_amdgcn_s_barrier();
        // ---- P1: (mh1,kh0) ----
        RD_A(1, 0);
        __builtin_amdgcn_s_barrier();
        LGKM0;
        __builtin_amdgcn_s_setprio(1); MM(1); __builtin_amdgcn_s_setprio(0);
        __builtin_amdgcn_s_barrier();
        // ---- P2: (mh0,kh1)+B(kh1) ----
        RD_B(1); RD_A(0, 1);
        __builtin_amdgcn_s_barrier();
        LGKM0;
        __builtin_amdgcn_s_setprio(1); MM(0); __builtin_amdgcn_s_setprio(0);
        __builtin_amdgcn_s_barrier();
        // ---- P3: (mh1,kh1); tail: await next-step stage ----
        RD_A(1, 1);
        __builtin_amdgcn_s_barrier();
        LGKM0;
        __builtin_amdgcn_s_setprio(1); MM(1); __builtin_amdgcn_s_setprio(0);
        if (pre) asm volatile("s_waitcnt vmcnt(0)" ::: "memory");
        __builtin_amdgcn_s_barrier();
    }
#undef GL
#undef STAGE
#undef RD_A
#undef RD_B
#undef MM
#undef LGKM0

    // ---- fused activation epilogue (smem reused; all LDS reads retired) ----
    const int q4 = lane >> 4;
    const int o0 = (blockIdx.y & 7) * 64;
    const float* bb = bias + dir * 2048;
    h2* Lfiz = (h2*)smem;                          // [256][68] h2 rows (272 B)
    _Float16* Los = (_Float16*)(smem + 69632);     // [256][72] half rows (144 B)
#pragma unroll
    for (int fm = 0; fm < 8; ++fm) {
        const int ol = wm * 32 + fm * 4 + q4;      // 0..63
        const int o = o0 + ol;
        const float Bz = bb[o];
        const float Bf = bb[512 + o];
        const float Bo = bb[1024 + o];
        const float Bi = bb[1536 + o];
#pragma unroll
        for (int fn = 0; fn < 4; ++fn) {
            f32x4 v = acc[fm][fn];
            const float fg = sigm(v.y + Bf);
            const float iz = sigm(v.w + Bi) * tanh_fast(v.x + Bz);
            const float og = sigm(v.z + Bo);
            const int nl = wn * 64 + fn * 16 + (lane & 15);
            h2 p; p.x = (_Float16)fg; p.y = (_Float16)iz;
            Lfiz[nl * 68 + ol] = p;
            Los[nl * 72 + ol] = (_Float16)og;
        }
    }
    __syncthreads();
    h2* fz = fiz + (size_t)dir * PLANE;
    _Float16* ob = osb + (size_t)dir * PLANE;
#pragma unroll
    for (int l = 0; l < 8; ++l) {                  // 256 rows x 16 uint4 (fiz)
        const int idx = l * 512 + tid;
        const int row = idx >> 4;
        const int col = idx & 15;
        uint4 v = *(const uint4*)((const unsigned char*)smem + row * 272 + col * 16);
        ((uint4*)(fz + (size_t)(n0 + row) * 512 + o0))[col] = v;
    }
#pragma unroll
    for (int l = 0; l < 4; ++l) {                  // 256 rows x 8 uint4 (osb)
        const int idx = l * 512 + tid;
        const int row = idx >> 3;
        const int col = idx & 7;
        uint4 v = *(const uint4*)((const unsigned char*)smem + 69632 + row * 144 + col * 16);
        ((uint4*)(ob + (size_t)(n0 + row) * 512 + o0))[col] = v;
    }
    // ---- per-chunk scan summaries ----
    if (tid < 256) {
        const int ol = tid & 63;
        const int ch = tid >> 6;      // 4 chunks of 64 t per n-tile
        float F = 1.0f, S = 0.0f;
#pragma unroll
        for (int tt = 0; tt < 64; ++tt) {
            const h2 v = Lfiz[(ch * 64 + tt) * 68 + ol];
            const float fv = (float)v.x;
            F *= fv;
            S = fv * S + (float)v.y;
        }
        const int b = n0 >> 9;
        const int chg = ((n0 & 511) >> 6) + ch;
        const int o = o0 + ol;
        const int sidx = dir * 131072 + chg * 16384 + b * 512 + o;
        Fsum[sidx] = F;
        Ssum[sidx] = S;
    }
}

// ---------------- scan kernels ----------------

__global__ __launch_bounds__(256) void scan_B(
    const float* __restrict__ Fsum, const float* __restrict__ Ssum,
    float* __restrict__ cstart)
{
    const int i = blockIdx.x * 256 + threadIdx.x;  // 32768 = 2 dir * 16384
    const int base = (i >> 14) * 131072 + (i & 16383);
    float c = 0.0f;
    for (int ch = 0; ch < 8; ++ch) {
        cstart[base + ch * 16384] = c;
        c = Fsum[base + ch * 16384] * c + Ssum[base + ch * 16384];
    }
}

__global__ __launch_bounds__(256) void scan_C(
    const h2* __restrict__ fiz, const _Float16* __restrict__ osb,
    const float* __restrict__ cstart, float* __restrict__ out,
    unsigned short* __restrict__ h1bf,
    float* __restrict__ hn, int isLayer2)
{
    const int idx = blockIdx.x * 256 + threadIdx.x;  // 262144 = 2 dir * 131072
    const int dir = idx >> 17;
    const int rem = idx & 131071;
    const int o = rem & 511;
    const int b = (rem >> 9) & 31;
    const int chunk = rem >> 14;
    const int dirH = dir * 512;
    float c = cstart[idx];
    const h2* fz = fiz + (size_t)dir * PLANE;
    const _Float16* ob = osb + (size_t)dir * PLANE;
    const int tbase = chunk * 64;
    for (int tt = 0; tt < 64; ++tt) {
        const int t = tbase + tt;
        const size_t idxg = ((size_t)(b * 512 + t)) * 512 + o;
        const h2 v = fz[idxg];
        const float f = (float)v.x;
        const float iz = (float)v.y;
        const float os = (float)ob[idxg];
        c = f * c + iz;
        const float outv = os * c;
        if (isLayer2) {
            out[((size_t)t * Bn + b) * 1024 + dirH + o] = outv;
        } else {
            h1bf[((size_t)b * 514 + (t + 1)) * 1024 + dirH + o] = f2bf(outv);
        }
        const bool isLast = (dir == 0) ? (t == Tn - 2) : (t == 0);
        if (isLast) hn[(size_t)b * 1024 + dirH + o] = outv;
    }
}

extern "C" void kernel_launch(void* const* d_in, const int* in_sizes, int n_in,
                              void* d_out, int out_size, void* d_ws, size_t ws_size,
                              hipStream_t stream) {
    const float* x  = (const float*)d_in[0];
    const float* w0 = (const float*)d_in[1];
    const float* b0 = (const float*)d_in[2];
    const float* w1 = (const float*)d_in[3];
    const float* b1 = (const float*)d_in[4];
    float* out = (float*)d_out;
    float* ws = (float*)d_ws;

    h2* fiz        = (h2*)ws;                               // 2*PLANE h2 (16.7M f)
    _Float16* osb  = (_Float16*)(ws + 16777216);            // 2*PLANE half (8.4M f)
    float* Fsum    = ws + 16777216 + 8388608;               // 262144
    float* Ssum    = Fsum + 262144;
    float* cst     = Ssum + 262144;
    unsigned short* xbf  = (unsigned short*)(cst + 262144); // 32*514*512
    unsigned short* h1bf = xbf + (size_t)32 * 514 * 512;    // 32*514*1024
    unsigned short* w0bf = h1bf + (size_t)32 * 514 * 1024;  // 2*2048*1024
    unsigned short* w1bf = w0bf + (size_t)2 * 2048 * 1024;  // 2*2048*2048
    float* hn = out + 16777216;

    conv_x<<<4112, 256, 0, stream>>>(x, xbf);
    conv_w2<<<49152, 256, 0, stream>>>(w0, w1, w0bf, w1bf);
    zero_h1pad<<<256, 256, 0, stream>>>(h1bf);

    const dim3 gg(64, 16);  // x = n-tiles (fastest); y = dir*8 + mtile

    // ---- Layer 1 (both dirs fused) ----
    gate_gemm_bf16<512><<<gg, 512, 0, stream>>>(w0bf, xbf, b0, fiz, osb, Fsum, Ssum);
    scan_B<<<128, 256, 0, stream>>>(Fsum, Ssum, cst);
    scan_C<<<1024, 256, 0, stream>>>(fiz, osb, cst, out, h1bf, hn, 0);
    // ---- Layer 2 (both dirs fused) ----
    gate_gemm_bf16<1024><<<gg, 512, 0, stream>>>(w1bf, h1bf, b1, fiz, osb, Fsum, Ssum);
    scan_B<<<128, 256, 0, stream>>>(Fsum, Ssum, cst);
    scan_C<<<1024, 256, 0, stream>>>(fiz, osb, cst, out, h1bf, hn + 32768, 1);
}

// Round 2
// 642.628 us; speedup vs baseline: 1.1599x; 1.1599x over previous
//
#include <hip/hip_runtime.h>
#include <cstddef>
#include <cstdint>

#define Tn 512
#define Bn 32
#define Hn 512
static const size_t PLANE = 8388608; // Bn*Tn*Hn

typedef float f32x4 __attribute__((ext_vector_type(4)));
typedef __bf16 bf16x8 __attribute__((ext_vector_type(8)));
typedef _Float16 h2 __attribute__((ext_vector_type(2)));

__device__ __forceinline__ float sigm(float x) { return 1.0f / (1.0f + __expf(-x)); }
__device__ __forceinline__ float tanh_fast(float x) { return 2.0f / (1.0f + __expf(-2.0f * x)) - 1.0f; }
__device__ __forceinline__ unsigned short f2bf(float f) {
    unsigned int u = __float_as_uint(f);
    u += 0x7FFF + ((u >> 16) & 1);   // RNE
    return (unsigned short)(u >> 16);
}

// ---------------- conversion kernels ----------------

__global__ __launch_bounds__(256) void conv_x(const float* __restrict__ x,
                                              unsigned short* __restrict__ xbf) {
    const int i = blockIdx.x * 256 + threadIdx.x;  // 32*514*64
    const int c8 = i & 63;
    const int tp = (i >> 6) % 514;
    const int b  = (i >> 6) / 514;
    unsigned short v[8];
    if (tp == 0 || tp == 513) {
#pragma unroll
        for (int j = 0; j < 8; ++j) v[j] = 0;
    } else {
        const float* s = x + ((size_t)(tp - 1) * Bn + b) * 512 + c8 * 8;
#pragma unroll
        for (int j = 0; j < 8; ++j) v[j] = f2bf(s[j]);
    }
    unsigned short* d = xbf + ((size_t)b * 514 + tp) * 512 + c8 * 8;
    *(uint4*)d = *(const uint4*)v;
}

// both weight tensors: [dir][g][o][c][tap] fp32 -> [dir][m'=o*4+g][k'=tap*Cin+c] bf16
__global__ __launch_bounds__(256) void conv_w2(const float* __restrict__ w0,
                                               const float* __restrict__ w1,
                                               unsigned short* __restrict__ w0bf,
                                               unsigned short* __restrict__ w1bf) {
    int i = blockIdx.x * 256 + threadIdx.x;   // 4194304 + 8388608
    const float* src;
    unsigned short* dst;
    int Cin;
    if (i < 4194304) { src = w0; dst = w0bf; Cin = 512; }
    else { i -= 4194304; src = w1; dst = w1bf; Cin = 1024; }
    const int K = 2 * Cin;
    const int dm2 = i / K;            // dir*2048 + m'
    const int kp = i - dm2 * K;
    const int dir = dm2 >> 11;
    const int mp = dm2 & 2047;
    const int o = mp >> 2;
    const int g = mp & 3;
    const int tap = (kp >= Cin) ? 1 : 0;
    const int c = kp - tap * Cin;
    dst[i] = f2bf(src[((((size_t)dir * 4 + g) * 512 + o) * Cin + c) * 2 + tap]);
}

__global__ __launch_bounds__(256) void zero_h1pad(unsigned short* __restrict__ h1bf) {
    const int i = blockIdx.x * 256 + threadIdx.x;  // 65536
    const int c = i & 1023;
    const int b = (i >> 10) & 31;
    const int tp = (i >> 15) ? 513 : 0;
    h1bf[((size_t)b * 514 + tp) * 1024 + c] = 0;
}

// ---------------- 256x256-tile 8-wave MFMA gate GEMM, 4-slot LDS ring ----------
// grid (64 n-tiles, 16): blockIdx.y = dir*8 + mtile (256 m-rows each).
// BK=32 per step; LDS ring of 4 slots x (A[256][32] + B[256][32]) = 128 KiB.
// Stage step s+3 issued at P0 of step s; counted vmcnt(8) at end of step
// (never 0 in steady state) -> 6-phase issue->need lead (T3+T4).
// Per step: 2 phases x {ds_read, barrier, lgkm0, setprio MFMA, barrier} (T5).
// 4-group XOR swizzle, same involution on pre-swizzled source + read (T2).
template <int CIN>
__global__ __launch_bounds__(512, 2) void gate_gemm_bf16(
    const unsigned short* __restrict__ Wbf,  // [2][2048][2*CIN], rows m'=o*4+g
    const unsigned short* __restrict__ Xbf,  // [32][514][CIN]
    const float* __restrict__ bias,          // [2][4][512]
    h2* __restrict__ fiz,                    // [2][16384][512]
    _Float16* __restrict__ osb,              // [2][16384][512]
    float* __restrict__ Fsum,                // [2][8][32][512]
    float* __restrict__ Ssum)                // [2][8][32][512]
{
    __shared__ __align__(16) unsigned char smem[131072];
    unsigned short* lds0 = (unsigned short*)smem;  // 4 x [A 8192][B 8192] elems

    const int tid = threadIdx.x;
    const int lane = tid & 63;
    const int wave = tid >> 6;
    const int wm = wave >> 2;          // 0..1 (M half)
    const int wn = wave & 3;           // 0..3 (N quarter)
    const int n0 = blockIdx.x * 256;
    const int dir = blockIdx.y >> 3;
    const int m0 = (blockIdx.y & 7) * 256;
    const int S32 = CIN / 32;
    const int NS = 2 * S32;            // BK=32 K-steps (tap-major)
    const int dstep = dir ? -CIN : CIN;

    const unsigned short* Wb = Wbf + (size_t)dir * 2048 * 2 * CIN;

    // ---- hoisted stage sources (4-group XOR swizzle baked into global addr) ----
    const unsigned short* pA2[2];
    const unsigned short* pB2[2];
#pragma unroll
    for (int c = 0; c < 2; ++c) {
        const int row = c * 128 + (tid >> 2);      // 0..255
        const int kk = (tid & 3) ^ ((row >> 1) & 3);
        pA2[c] = Wb + (size_t)(m0 + row) * (2 * CIN) + kk * 8;
        const int n = n0 + row;
        const int t = n & 511;
        const int b = n >> 9;
        const int tp0 = dir ? (513 - t) : t;
        pB2[c] = Xbf + ((size_t)b * 514 + tp0) * CIN + kk * 8;
    }

    // ---- hoisted LDS fragment offsets (elements within slot) ----
    const int jr0 = lane >> 4;
    int offA[8], offB[4];
#pragma unroll
    for (int f = 0; f < 8; ++f) {
        const int ma = wm * 128 + f * 16 + (lane & 15);
        offA[f] = ma * 32 + (jr0 ^ ((ma >> 1) & 3)) * 8;
    }
#pragma unroll
    for (int f = 0; f < 4; ++f) {
        const int nb = wn * 64 + f * 16 + (lane & 15);
        offB[f] = nb * 32 + (jr0 ^ ((nb >> 1) & 3)) * 8;
    }

    f32x4 acc[8][4] = {};

#define GL(P, D) __builtin_amdgcn_global_load_lds( \
        (const __attribute__((address_space(1))) unsigned int*)(P), \
        (__attribute__((address_space(3))) unsigned int*)(D), 16, 0, 0)

#define STAGE(ks) do { \
    const int tap_ = ((ks) >= S32) ? 1 : 0; \
    const int aoff_ = tap_ * CIN + ((ks) - tap_ * S32) * 32; \
    const int boff_ = tap_ * dstep + ((ks) - tap_ * S32) * 32; \
    unsigned short* D_ = lds0 + ((ks) & 3) * 16384 + tid * 8; \
    GL(pA2[0] + aoff_, D_);          GL(pA2[1] + aoff_, D_ + 4096); \
    GL(pB2[0] + boff_, D_ + 8192);   GL(pB2[1] + boff_, D_ + 12288); \
} while (0)

#define RD_A(mh) do { \
    af[0] = *(const bf16x8*)&Ab[offA[(mh)*4+0]]; \
    af[1] = *(const bf16x8*)&Ab[offA[(mh)*4+1]]; \
    af[2] = *(const bf16x8*)&Ab[offA[(mh)*4+2]]; \
    af[3] = *(const bf16x8*)&Ab[offA[(mh)*4+3]]; \
} while (0)

#define RD_B() do { \
    bfr[0] = *(const bf16x8*)&Bb[offB[0]]; \
    bfr[1] = *(const bf16x8*)&Bb[offB[1]]; \
    bfr[2] = *(const bf16x8*)&Bb[offB[2]]; \
    bfr[3] = *(const bf16x8*)&Bb[offB[3]]; \
} while (0)

#define MM(mh) do { \
    _Pragma("unroll") \
    for (int f_ = 0; f_ < 4; ++f_) { \
        _Pragma("unroll") \
        for (int fn_ = 0; fn_ < 4; ++fn_) \
            acc[(mh)*4+f_][fn_] = __builtin_amdgcn_mfma_f32_16x16x32_bf16( \
                af[f_], bfr[fn_], acc[(mh)*4+f_][fn_], 0, 0, 0); \
    } \
} while (0)

#define LGKM0 do { asm volatile("s_waitcnt lgkmcnt(0)" ::: "memory"); \
                   __builtin_amdgcn_sched_barrier(0); } while (0)

    // ---- prologue: 3 stage-groups in flight, wait only for the first ----
    STAGE(0); STAGE(1); STAGE(2);
    asm volatile("s_waitcnt vmcnt(8)" ::: "memory");
    __builtin_amdgcn_s_barrier();

#pragma unroll 4
    for (int s = 0; s < NS; ++s) {
        asm volatile("" ::: "memory");
        const unsigned short* Ab = lds0 + (s & 3) * 16384;
        const unsigned short* Bb = Ab + 8192;
        bf16x8 af[4], bfr[4];
        // ---- P0: read B + A(mh0), issue stage(s+3), MFMA quad ----
        RD_B(); RD_A(0);
        if (s + 3 < NS) STAGE(s + 3);
        __builtin_amdgcn_s_barrier();
        LGKM0;
        __builtin_amdgcn_s_setprio(1); MM(0); __builtin_amdgcn_s_setprio(0);
        __builtin_amdgcn_s_barrier();
        // ---- P1: A(mh1); tail: counted wait for stage(s+1) ----
        RD_A(1);
        __builtin_amdgcn_s_barrier();
        LGKM0;
        __builtin_amdgcn_s_setprio(1); MM(1); __builtin_amdgcn_s_setprio(0);
        if (s + 3 < NS)      { asm volatile("s_waitcnt vmcnt(8)" ::: "memory"); }
        else if (s + 2 < NS) { asm volatile("s_waitcnt vmcnt(4)" ::: "memory"); }
        else if (s + 1 < NS) { asm volatile("s_waitcnt vmcnt(0)" ::: "memory"); }
        __builtin_amdgcn_s_barrier();
    }
#undef GL
#undef STAGE
#undef RD_A
#undef RD_B
#undef MM
#undef LGKM0

    // ---- fused activation epilogue (smem reused; all LDS reads retired) ----
    const int q4 = lane >> 4;
    const int o0 = (blockIdx.y & 7) * 64;
    const float* bb = bias + dir * 2048;
    h2* Lfiz = (h2*)smem;                          // [256][68] h2 rows (272 B)
    _Float16* Los = (_Float16*)(smem + 69632);     // [256][72] half rows (144 B)
#pragma unroll
    for (int fm = 0; fm < 8; ++fm) {
        const int ol = wm * 32 + fm * 4 + q4;      // 0..63
        const int o = o0 + ol;
        const float Bz = bb[o];
        const float Bf = bb[512 + o];
        const float Bo = bb[1024 + o];
        const float Bi = bb[1536 + o];
#pragma unroll
        for (int fn = 0; fn < 4; ++fn) {
            f32x4 v = acc[fm][fn];
            const float fg = sigm(v.y + Bf);
            const float iz = sigm(v.w + Bi) * tanh_fast(v.x + Bz);
            const float og = sigm(v.z + Bo);
            const int nl = wn * 64 + fn * 16 + (lane & 15);
            h2 p; p.x = (_Float16)fg; p.y = (_Float16)iz;
            Lfiz[nl * 68 + ol] = p;
            Los[nl * 72 + ol] = (_Float16)og;
        }
    }
    __syncthreads();
    h2* fz = fiz + (size_t)dir * PLANE;
    _Float16* ob = osb + (size_t)dir * PLANE;
#pragma unroll
    for (int l = 0; l < 8; ++l) {                  // 256 rows x 16 uint4 (fiz)
        const int idx = l * 512 + tid;
        const int row = idx >> 4;
        const int col = idx & 15;
        uint4 v = *(const uint4*)((const unsigned char*)smem + row * 272 + col * 16);
        ((uint4*)(fz + (size_t)(n0 + row) * 512 + o0))[col] = v;
    }
#pragma unroll
    for (int l = 0; l < 4; ++l) {                  // 256 rows x 8 uint4 (osb)
        const int idx = l * 512 + tid;
        const int row = idx >> 3;
        const int col = idx & 7;
        uint4 v = *(const uint4*)((const unsigned char*)smem + 69632 + row * 144 + col * 16);
        ((uint4*)(ob + (size_t)(n0 + row) * 512 + o0))[col] = v;
    }
    // ---- per-chunk scan summaries ----
    if (tid < 256) {
        const int ol = tid & 63;
        const int ch = tid >> 6;      // 4 chunks of 64 t per n-tile
        float F = 1.0f, S = 0.0f;
#pragma unroll
        for (int tt = 0; tt < 64; ++tt) {
            const h2 v = Lfiz[(ch * 64 + tt) * 68 + ol];
            const float fv = (float)v.x;
            F *= fv;
            S = fv * S + (float)v.y;
        }
        const int b = n0 >> 9;
        const int chg = ((n0 & 511) >> 6) + ch;
        const int o = o0 + ol;
        const int sidx = dir * 131072 + chg * 16384 + b * 512 + o;
        Fsum[sidx] = F;
        Ssum[sidx] = S;
    }
}

// ---------------- scan kernels ----------------

__global__ __launch_bounds__(256) void scan_B(
    const float* __restrict__ Fsum, const float* __restrict__ Ssum,
    float* __restrict__ cstart)
{
    const int i = blockIdx.x * 256 + threadIdx.x;  // 32768 = 2 dir * 16384
    const int base = (i >> 14) * 131072 + (i & 16383);
    float c = 0.0f;
    for (int ch = 0; ch < 8; ++ch) {
        cstart[base + ch * 16384] = c;
        c = Fsum[base + ch * 16384] * c + Ssum[base + ch * 16384];
    }
}

__global__ __launch_bounds__(256) void scan_C(
    const h2* __restrict__ fiz, const _Float16* __restrict__ osb,
    const float* __restrict__ cstart, float* __restrict__ out,
    unsigned short* __restrict__ h1bf,
    float* __restrict__ hn, int isLayer2)
{
    const int idx = blockIdx.x * 256 + threadIdx.x;  // 262144 = 2 dir * 131072
    const int dir = idx >> 17;
    const int rem = idx & 131071;
    const int o = rem & 511;
    const int b = (rem >> 9) & 31;
    const int chunk = rem >> 14;
    const int dirH = dir * 512;
    float c = cstart[idx];
    const h2* fz = fiz + (size_t)dir * PLANE;
    const _Float16* ob = osb + (size_t)dir * PLANE;
    const int tbase = chunk * 64;
    for (int tt = 0; tt < 64; ++tt) {
        const int t = tbase + tt;
        const size_t idxg = ((size_t)(b * 512 + t)) * 512 + o;
        const h2 v = fz[idxg];
        const float f = (float)v.x;
        const float iz = (float)v.y;
        const float os = (float)ob[idxg];
        c = f * c + iz;
        const float outv = os * c;
        if (isLayer2) {
            out[((size_t)t * Bn + b) * 1024 + dirH + o] = outv;
        } else {
            h1bf[((size_t)b * 514 + (t + 1)) * 1024 + dirH + o] = f2bf(outv);
        }
        const bool isLast = (dir == 0) ? (t == Tn - 2) : (t == 0);
        if (isLast) hn[(size_t)b * 1024 + dirH + o] = outv;
    }
}

extern "C" void kernel_launch(void* const* d_in, const int* in_sizes, int n_in,
                              void* d_out, int out_size, void* d_ws, size_t ws_size,
                              hipStream_t stream) {
    const float* x  = (const float*)d_in[0];
    const float* w0 = (const float*)d_in[1];
    const float* b0 = (const float*)d_in[2];
    const float* w1 = (const float*)d_in[3];
    const float* b1 = (const float*)d_in[4];
    float* out = (float*)d_out;
    float* ws = (float*)d_ws;

    h2* fiz        = (h2*)ws;                               // 2*PLANE h2 (16.7M f)
    _Float16* osb  = (_Float16*)(ws + 16777216);            // 2*PLANE half (8.4M f)
    float* Fsum    = ws + 16777216 + 8388608;               // 262144
    float* Ssum    = Fsum + 262144;
    float* cst     = Ssum + 262144;
    unsigned short* xbf  = (unsigned short*)(cst + 262144); // 32*514*512
    unsigned short* h1bf = xbf + (size_t)32 * 514 * 512;    // 32*514*1024
    unsigned short* w0bf = h1bf + (size_t)32 * 514 * 1024;  // 2*2048*1024
    unsigned short* w1bf = w0bf + (size_t)2 * 2048 * 1024;  // 2*2048*2048
    float* hn = out + 16777216;

    conv_x<<<4112, 256, 0, stream>>>(x, xbf);
    conv_w2<<<49152, 256, 0, stream>>>(w0, w1, w0bf, w1bf);
    zero_h1pad<<<256, 256, 0, stream>>>(h1bf);

    const dim3 gg(64, 16);  // x = n-tiles (fastest); y = dir*8 + mtile

    // ---- Layer 1 (both dirs fused) ----
    gate_gemm_bf16<512><<<gg, 512, 0, stream>>>(w0bf, xbf, b0, fiz, osb, Fsum, Ssum);
    scan_B<<<128, 256, 0, stream>>>(Fsum, Ssum, cst);
    scan_C<<<1024, 256, 0, stream>>>(fiz, osb, cst, out, h1bf, hn, 0);
    // ---- Layer 2 (both dirs fused) ----
    gate_gemm_bf16<1024><<<gg, 512, 0, stream>>>(w1bf, h1bf, b1, fiz, osb, Fsum, Ssum);
    scan_B<<<128, 256, 0, stream>>>(Fsum, Ssum, cst);
    scan_C<<<1024, 256, 0, stream>>>(fiz, osb, cst, out, h1bf, hn + 32768, 1);
}

// Round 3
// 598.364 us; speedup vs baseline: 1.2457x; 1.0740x over previous
//
#include <hip/hip_runtime.h>
#include <cstddef>
#include <cstdint>

#define Tn 512
#define Bn 32
#define Hn 512
static const size_t PLANE = 8388608; // Bn*Tn*Hn

typedef float f32x4 __attribute__((ext_vector_type(4)));
typedef __bf16 bf16x8 __attribute__((ext_vector_type(8)));
typedef _Float16 h2 __attribute__((ext_vector_type(2)));

__device__ __forceinline__ float sigm(float x) { return 1.0f / (1.0f + __expf(-x)); }
__device__ __forceinline__ float tanh_fast(float x) { return 2.0f / (1.0f + __expf(-2.0f * x)) - 1.0f; }
__device__ __forceinline__ unsigned short f2bf(float f) {
    unsigned int u = __float_as_uint(f);
    u += 0x7FFF + ((u >> 16) & 1);   // RNE
    return (unsigned short)(u >> 16);
}

// ---------------- conversion kernels ----------------

__global__ __launch_bounds__(256) void conv_x(const float* __restrict__ x,
                                              unsigned short* __restrict__ xbf) {
    const int i = blockIdx.x * 256 + threadIdx.x;  // 32*514*64
    const int c8 = i & 63;
    const int tp = (i >> 6) % 514;
    const int b  = (i >> 6) / 514;
    unsigned short v[8];
    if (tp == 0 || tp == 513) {
#pragma unroll
        for (int j = 0; j < 8; ++j) v[j] = 0;
    } else {
        const float* s = x + ((size_t)(tp - 1) * Bn + b) * 512 + c8 * 8;
#pragma unroll
        for (int j = 0; j < 8; ++j) v[j] = f2bf(s[j]);
    }
    unsigned short* d = xbf + ((size_t)b * 514 + tp) * 512 + c8 * 8;
    *(uint4*)d = *(const uint4*)v;
}

// both weight tensors: [dir][g][o][c][tap] fp32 -> [dir][m'=o*4+g][k'=tap*Cin+c] bf16
__global__ __launch_bounds__(256) void conv_w2(const float* __restrict__ w0,
                                               const float* __restrict__ w1,
                                               unsigned short* __restrict__ w0bf,
                                               unsigned short* __restrict__ w1bf) {
    int i = blockIdx.x * 256 + threadIdx.x;   // 4194304 + 8388608
    const float* src;
    unsigned short* dst;
    int Cin;
    if (i < 4194304) { src = w0; dst = w0bf; Cin = 512; }
    else { i -= 4194304; src = w1; dst = w1bf; Cin = 1024; }
    const int K = 2 * Cin;
    const int dm2 = i / K;            // dir*2048 + m'
    const int kp = i - dm2 * K;
    const int dir = dm2 >> 11;
    const int mp = dm2 & 2047;
    const int o = mp >> 2;
    const int g = mp & 3;
    const int tap = (kp >= Cin) ? 1 : 0;
    const int c = kp - tap * Cin;
    dst[i] = f2bf(src[((((size_t)dir * 4 + g) * 512 + o) * Cin + c) * 2 + tap]);
}

__global__ __launch_bounds__(256) void zero_h1pad(unsigned short* __restrict__ h1bf) {
    const int i = blockIdx.x * 256 + threadIdx.x;  // 65536
    const int c = i & 1023;
    const int b = (i >> 10) & 31;
    const int tp = (i >> 15) ? 513 : 0;
    h1bf[((size_t)b * 514 + tp) * 1024 + c] = 0;
}

// ---------------- 256x256-tile 8-wave MFMA gate GEMM, 4-slot LDS ring ----------
// grid (64 n-tiles, 16): blockIdx.y = dir*8 + mtile (256 m-rows each).
// BK=32 per step; LDS ring of 4 slots x (A[256][32] + B[256][32]) = 128 KiB.
// Stage step s+3 issued at top of step s; counted vmcnt(8) at end of step
// (never 0 in steady state) -> slot s+1 guaranteed at the single per-step
// barrier (T3+T4). ONE barrier per step: slot-readiness needs all waves'
// DMA confirmed (vmcnt is per-wave); overwrite distance (ring-4) is covered
// by the same barrier. No intra-step barriers / lgkmcnt(0): the compiler's
// fine-grained lgkmcnt interleave + 2-wave/SIMD skew overlap DS and MFMA
// pipes (m97/m114 mechanism). setprio(1) across the MFMA tail (T5).
// 4-group XOR swizzle, same involution on pre-swizzled source + read (T2).
template <int CIN>
__global__ __launch_bounds__(512, 2) void gate_gemm_bf16(
    const unsigned short* __restrict__ Wbf,  // [2][2048][2*CIN], rows m'=o*4+g
    const unsigned short* __restrict__ Xbf,  // [32][514][CIN]
    const float* __restrict__ bias,          // [2][4][512]
    h2* __restrict__ fiz,                    // [2][16384][512]
    _Float16* __restrict__ osb,              // [2][16384][512]
    float* __restrict__ Fsum,                // [2][8][32][512]
    float* __restrict__ Ssum)                // [2][8][32][512]
{
    __shared__ __align__(16) unsigned char smem[131072];
    unsigned short* lds0 = (unsigned short*)smem;  // 4 x [A 8192][B 8192] elems

    const int tid = threadIdx.x;
    const int lane = tid & 63;
    const int wave = tid >> 6;
    const int wm = wave >> 2;          // 0..1 (M half)
    const int wn = wave & 3;           // 0..3 (N quarter)
    const int n0 = blockIdx.x * 256;
    const int dir = blockIdx.y >> 3;
    const int m0 = (blockIdx.y & 7) * 256;
    const int S32 = CIN / 32;
    const int NS = 2 * S32;            // BK=32 K-steps (tap-major)
    const int dstep = dir ? -CIN : CIN;

    const unsigned short* Wb = Wbf + (size_t)dir * 2048 * 2 * CIN;

    // ---- hoisted stage sources (4-group XOR swizzle baked into global addr) ----
    const unsigned short* pA2[2];
    const unsigned short* pB2[2];
#pragma unroll
    for (int c = 0; c < 2; ++c) {
        const int row = c * 128 + (tid >> 2);      // 0..255
        const int kk = (tid & 3) ^ ((row >> 1) & 3);
        pA2[c] = Wb + (size_t)(m0 + row) * (2 * CIN) + kk * 8;
        const int n = n0 + row;
        const int t = n & 511;
        const int b = n >> 9;
        const int tp0 = dir ? (513 - t) : t;
        pB2[c] = Xbf + ((size_t)b * 514 + tp0) * CIN + kk * 8;
    }

    // ---- hoisted LDS fragment offsets (elements within slot) ----
    const int jr0 = lane >> 4;
    int offA[8], offB[4];
#pragma unroll
    for (int f = 0; f < 8; ++f) {
        const int ma = wm * 128 + f * 16 + (lane & 15);
        offA[f] = ma * 32 + (jr0 ^ ((ma >> 1) & 3)) * 8;
    }
#pragma unroll
    for (int f = 0; f < 4; ++f) {
        const int nb = wn * 64 + f * 16 + (lane & 15);
        offB[f] = nb * 32 + (jr0 ^ ((nb >> 1) & 3)) * 8;
    }

    f32x4 acc[8][4] = {};

#define GL(P, D) __builtin_amdgcn_global_load_lds( \
        (const __attribute__((address_space(1))) unsigned int*)(P), \
        (__attribute__((address_space(3))) unsigned int*)(D), 16, 0, 0)

#define STAGE(ks) do { \
    const int tap_ = ((ks) >= S32) ? 1 : 0; \
    const int aoff_ = tap_ * CIN + ((ks) - tap_ * S32) * 32; \
    const int boff_ = tap_ * dstep + ((ks) - tap_ * S32) * 32; \
    unsigned short* D_ = lds0 + ((ks) & 3) * 16384 + tid * 8; \
    GL(pA2[0] + aoff_, D_);          GL(pA2[1] + aoff_, D_ + 4096); \
    GL(pB2[0] + boff_, D_ + 8192);   GL(pB2[1] + boff_, D_ + 12288); \
} while (0)

#define RD_A(mh) do { \
    af[0] = *(const bf16x8*)&Ab[offA[(mh)*4+0]]; \
    af[1] = *(const bf16x8*)&Ab[offA[(mh)*4+1]]; \
    af[2] = *(const bf16x8*)&Ab[offA[(mh)*4+2]]; \
    af[3] = *(const bf16x8*)&Ab[offA[(mh)*4+3]]; \
} while (0)

#define RD_B() do { \
    bfr[0] = *(const bf16x8*)&Bb[offB[0]]; \
    bfr[1] = *(const bf16x8*)&Bb[offB[1]]; \
    bfr[2] = *(const bf16x8*)&Bb[offB[2]]; \
    bfr[3] = *(const bf16x8*)&Bb[offB[3]]; \
} while (0)

#define MM(mh) do { \
    _Pragma("unroll") \
    for (int f_ = 0; f_ < 4; ++f_) { \
        _Pragma("unroll") \
        for (int fn_ = 0; fn_ < 4; ++fn_) \
            acc[(mh)*4+f_][fn_] = __builtin_amdgcn_mfma_f32_16x16x32_bf16( \
                af[f_], bfr[fn_], acc[(mh)*4+f_][fn_], 0, 0, 0); \
    } \
} while (0)

    // ---- prologue: 3 stage-groups in flight, wait only for the first ----
    STAGE(0); STAGE(1); STAGE(2);
    asm volatile("s_waitcnt vmcnt(8)" ::: "memory");
    __builtin_amdgcn_s_barrier();

#pragma unroll 4
    for (int s = 0; s < NS; ++s) {
        asm volatile("" ::: "memory");   // pin LDS reads below the barrier
        const unsigned short* Ab = lds0 + (s & 3) * 16384;
        const unsigned short* Bb = Ab + 8192;
        bf16x8 af[4], bfr[4];
        // issue current-step operand reads + next+2 stage; no intra-step
        // barriers -- compiler emits fine-grained lgkmcnt, waves skew.
        RD_B(); RD_A(0);
        if (s + 3 < NS) STAGE(s + 3);
        __builtin_amdgcn_s_setprio(1);
        MM(0);
        RD_A(1);                         // reuses af regs (WAR keeps order)
        MM(1);
        __builtin_amdgcn_s_setprio(0);
        // counted wait: slot s+1 guaranteed after the barrier
        if (s + 3 < NS)      { asm volatile("s_waitcnt vmcnt(8)" ::: "memory"); }
        else if (s + 2 < NS) { asm volatile("s_waitcnt vmcnt(4)" ::: "memory"); }
        else if (s + 1 < NS) { asm volatile("s_waitcnt vmcnt(0)" ::: "memory"); }
        __builtin_amdgcn_s_barrier();
    }
#undef GL
#undef STAGE
#undef RD_A
#undef RD_B
#undef MM

    // ---- fused activation epilogue (smem reused; all LDS reads retired) ----
    asm volatile("" ::: "memory");
    const int q4 = lane >> 4;
    const int o0 = (blockIdx.y & 7) * 64;
    const float* bb = bias + dir * 2048;
    h2* Lfiz = (h2*)smem;                          // [256][68] h2 rows (272 B)
    _Float16* Los = (_Float16*)(smem + 69632);     // [256][72] half rows (144 B)
#pragma unroll
    for (int fm = 0; fm < 8; ++fm) {
        const int ol = wm * 32 + fm * 4 + q4;      // 0..63
        const int o = o0 + ol;
        const float Bz = bb[o];
        const float Bf = bb[512 + o];
        const float Bo = bb[1024 + o];
        const float Bi = bb[1536 + o];
#pragma unroll
        for (int fn = 0; fn < 4; ++fn) {
            f32x4 v = acc[fm][fn];
            const float fg = sigm(v.y + Bf);
            const float iz = sigm(v.w + Bi) * tanh_fast(v.x + Bz);
            const float og = sigm(v.z + Bo);
            const int nl = wn * 64 + fn * 16 + (lane & 15);
            h2 p; p.x = (_Float16)fg; p.y = (_Float16)iz;
            Lfiz[nl * 68 + ol] = p;
            Los[nl * 72 + ol] = (_Float16)og;
        }
    }
    __syncthreads();
    h2* fz = fiz + (size_t)dir * PLANE;
    _Float16* ob = osb + (size_t)dir * PLANE;
#pragma unroll
    for (int l = 0; l < 8; ++l) {                  // 256 rows x 16 uint4 (fiz)
        const int idx = l * 512 + tid;
        const int row = idx >> 4;
        const int col = idx & 15;
        uint4 v = *(const uint4*)((const unsigned char*)smem + row * 272 + col * 16);
        ((uint4*)(fz + (size_t)(n0 + row) * 512 + o0))[col] = v;
    }
#pragma unroll
    for (int l = 0; l < 4; ++l) {                  // 256 rows x 8 uint4 (osb)
        const int idx = l * 512 + tid;
        const int row = idx >> 3;
        const int col = idx & 7;
        uint4 v = *(const uint4*)((const unsigned char*)smem + 69632 + row * 144 + col * 16);
        ((uint4*)(ob + (size_t)(n0 + row) * 512 + o0))[col] = v;
    }
    // ---- per-chunk scan summaries ----
    if (tid < 256) {
        const int ol = tid & 63;
        const int ch = tid >> 6;      // 4 chunks of 64 t per n-tile
        float F = 1.0f, S = 0.0f;
#pragma unroll
        for (int tt = 0; tt < 64; ++tt) {
            const h2 v = Lfiz[(ch * 64 + tt) * 68 + ol];
            const float fv = (float)v.x;
            F *= fv;
            S = fv * S + (float)v.y;
        }
        const int b = n0 >> 9;
        const int chg = ((n0 & 511) >> 6) + ch;
        const int o = o0 + ol;
        const int sidx = dir * 131072 + chg * 16384 + b * 512 + o;
        Fsum[sidx] = F;
        Ssum[sidx] = S;
    }
}

// ---------------- scan kernels ----------------

__global__ __launch_bounds__(256) void scan_B(
    const float* __restrict__ Fsum, const float* __restrict__ Ssum,
    float* __restrict__ cstart)
{
    const int i = blockIdx.x * 256 + threadIdx.x;  // 32768 = 2 dir * 16384
    const int base = (i >> 14) * 131072 + (i & 16383);
    float c = 0.0f;
    for (int ch = 0; ch < 8; ++ch) {
        cstart[base + ch * 16384] = c;
        c = Fsum[base + ch * 16384] * c + Ssum[base + ch * 16384];
    }
}

__global__ __launch_bounds__(256) void scan_C(
    const h2* __restrict__ fiz, const _Float16* __restrict__ osb,
    const float* __restrict__ cstart, float* __restrict__ out,
    unsigned short* __restrict__ h1bf,
    float* __restrict__ hn, int isLayer2)
{
    const int idx = blockIdx.x * 256 + threadIdx.x;  // 262144 = 2 dir * 131072
    const int dir = idx >> 17;
    const int rem = idx & 131071;
    const int o = rem & 511;
    const int b = (rem >> 9) & 31;
    const int chunk = rem >> 14;
    const int dirH = dir * 512;
    float c = cstart[idx];
    const h2* fz = fiz + (size_t)dir * PLANE;
    const _Float16* ob = osb + (size_t)dir * PLANE;
    const int tbase = chunk * 64;
    for (int tt = 0; tt < 64; ++tt) {
        const int t = tbase + tt;
        const size_t idxg = ((size_t)(b * 512 + t)) * 512 + o;
        const h2 v = fz[idxg];
        const float f = (float)v.x;
        const float iz = (float)v.y;
        const float os = (float)ob[idxg];
        c = f * c + iz;
        const float outv = os * c;
        if (isLayer2) {
            out[((size_t)t * Bn + b) * 1024 + dirH + o] = outv;
        } else {
            h1bf[((size_t)b * 514 + (t + 1)) * 1024 + dirH + o] = f2bf(outv);
        }
        const bool isLast = (dir == 0) ? (t == Tn - 2) : (t == 0);
        if (isLast) hn[(size_t)b * 1024 + dirH + o] = outv;
    }
}

extern "C" void kernel_launch(void* const* d_in, const int* in_sizes, int n_in,
                              void* d_out, int out_size, void* d_ws, size_t ws_size,
                              hipStream_t stream) {
    const float* x  = (const float*)d_in[0];
    const float* w0 = (const float*)d_in[1];
    const float* b0 = (const float*)d_in[2];
    const float* w1 = (const float*)d_in[3];
    const float* b1 = (const float*)d_in[4];
    float* out = (float*)d_out;
    float* ws = (float*)d_ws;

    h2* fiz        = (h2*)ws;                               // 2*PLANE h2 (16.7M f)
    _Float16* osb  = (_Float16*)(ws + 16777216);            // 2*PLANE half (8.4M f)
    float* Fsum    = ws + 16777216 + 8388608;               // 262144
    float* Ssum    = Fsum + 262144;
    float* cst     = Ssum + 262144;
    unsigned short* xbf  = (unsigned short*)(cst + 262144); // 32*514*512
    unsigned short* h1bf = xbf + (size_t)32 * 514 * 512;    // 32*514*1024
    unsigned short* w0bf = h1bf + (size_t)32 * 514 * 1024;  // 2*2048*1024
    unsigned short* w1bf = w0bf + (size_t)2 * 2048 * 1024;  // 2*2048*2048
    float* hn = out + 16777216;

    conv_x<<<4112, 256, 0, stream>>>(x, xbf);
    conv_w2<<<49152, 256, 0, stream>>>(w0, w1, w0bf, w1bf);
    zero_h1pad<<<256, 256, 0, stream>>>(h1bf);

    const dim3 gg(64, 16);  // x = n-tiles (fastest); y = dir*8 + mtile

    // ---- Layer 1 (both dirs fused) ----
    gate_gemm_bf16<512><<<gg, 512, 0, stream>>>(w0bf, xbf, b0, fiz, osb, Fsum, Ssum);
    scan_B<<<128, 256, 0, stream>>>(Fsum, Ssum, cst);
    scan_C<<<1024, 256, 0, stream>>>(fiz, osb, cst, out, h1bf, hn, 0);
    // ---- Layer 2 (both dirs fused) ----
    gate_gemm_bf16<1024><<<gg, 512, 0, stream>>>(w1bf, h1bf, b1, fiz, osb, Fsum, Ssum);
    scan_B<<<128, 256, 0, stream>>>(Fsum, Ssum, cst);
    scan_C<<<1024, 256, 0, stream>>>(fiz, osb, cst, out, h1bf, hn + 32768, 1);
}